// Round 2
// baseline (746.867 us; speedup 1.0000x reference)
//
#include <hip/hip_runtime.h>
#include <math.h>

#define S 2048
#define DD 2048
#define NH 16
#define DH 128
#define DHID 128
#define DKER 64
#define EPSF 1e-6f

typedef __attribute__((ext_vector_type(8))) short bf16x8;
typedef __attribute__((ext_vector_type(4))) float f32x4;

__device__ __forceinline__ float gelu_f(float x) {
    return 0.5f * x * (1.0f + erff(x * 0.7071067811865475f));
}

__device__ __forceinline__ ushort f2b(float x) {
    uint32_t u = __float_as_uint(x);
    uint32_t r = (u + 0x7FFFu + ((u >> 16) & 1u)) >> 16;
    return (ushort)r;
}

__device__ __forceinline__ bf16x8 pack8(float4 a, float4 b) {
    bf16x8 r;
    r[0] = (short)f2b(a.x); r[1] = (short)f2b(a.y);
    r[2] = (short)f2b(a.z); r[3] = (short)f2b(a.w);
    r[4] = (short)f2b(b.x); r[5] = (short)f2b(b.y);
    r[6] = (short)f2b(b.z); r[7] = (short)f2b(b.w);
    return r;
}

// ---- weight prep: transpose+convert to bf16 [out_dim][in_dim] ----
__global__ __launch_bounds__(256) void k_wprep(const float* __restrict__ wq1,
                                               const float* __restrict__ wk1,
                                               const float* __restrict__ wq2,
                                               const float* __restrict__ wk2,
                                               const float* __restrict__ ik,
                                               ushort* __restrict__ w1qt,
                                               ushort* __restrict__ w1kt,
                                               ushort* __restrict__ w2qt,
                                               ushort* __restrict__ w2kt,
                                               ushort* __restrict__ ikt) {
    const int h = blockIdx.x, m = blockIdx.y, tid = threadIdx.x;
    const float* src; ushort* dst; int D;
    if (m == 0)      { src = wq1 + h * 16384; dst = w1qt + h * 16384; D = 128; }
    else if (m == 1) { src = wk1 + h * 16384; dst = w1kt + h * 16384; D = 128; }
    else if (m == 2) { src = wq2 + h * 8192;  dst = w2qt + h * 8192;  D = 128; }
    else if (m == 3) { src = wk2 + h * 8192;  dst = w2kt + h * 8192;  D = 128; }
    else             { src = ik  + h * 4096;  dst = ikt  + h * 4096;  D = 64;  }
    const int E = (m == 0 || m == 1) ? 128 : 64;
    const int dsh = (D == 128) ? 7 : 6;
    const int n = E * D;
    for (int idx = tid; idx < n; idx += 256) {
        int e = idx >> dsh, d = idx & (D - 1);
        dst[idx] = f2b(src[d * E + e]);
    }
}

// ---- fused MLP paths: z=0 -> Q2abs, z=1 -> K3abs ----
__global__ __launch_bounds__(256) void k_fused(const float* __restrict__ Xq,
                                               const float* __restrict__ Xk,
                                               const ushort* __restrict__ w1qt,
                                               const ushort* __restrict__ w1kt,
                                               const ushort* __restrict__ w2qt,
                                               const ushort* __restrict__ w2kt,
                                               const ushort* __restrict__ ikt,
                                               const float* __restrict__ sD,
                                               const float* __restrict__ sD2,
                                               ushort* __restrict__ Q2,
                                               ushort* __restrict__ K3) {
    const int h = blockIdx.y;
    const int s0 = blockIdx.x * 64;
    const int z = blockIdx.z;
    const int tid = threadIdx.x;
    const int wv = tid >> 6, lane = tid & 63;
    const int ln = lane & 15, quad = lane >> 4;
    __shared__ ushort Y1s[64][136];   // 272B row ≡ 4 dw mod 32 banks
    __shared__ ushort K2s[64][72];

    const float* X = z ? Xk : Xq;
    const ushort* w1t = z ? w1kt : w1qt;
    const ushort* w2t = z ? w2kt : w2qt;

    // A1: X rows (fp32 -> bf16), direct from global
    const float* Xr = X + (size_t)(s0 + wv * 16 + ln) * DD + h * DH;
    bf16x8 a1[4];
    #pragma unroll
    for (int ks = 0; ks < 4; ++ks)
        a1[ks] = pack8(*(const float4*)(Xr + ks * 32 + quad * 8),
                       *(const float4*)(Xr + ks * 32 + quad * 8 + 4));

    // mlp1: 64x128 @ 128x128
    const ushort* W1h = w1t + (size_t)h * DH * DHID;
    f32x4 c1[8];
    #pragma unroll
    for (int n = 0; n < 8; ++n) c1[n] = (f32x4){0.f, 0.f, 0.f, 0.f};
    #pragma unroll
    for (int n = 0; n < 8; ++n)
        #pragma unroll
        for (int ks = 0; ks < 4; ++ks) {
            bf16x8 b = *(const bf16x8*)(W1h + (size_t)(n * 16 + ln) * DHID +
                                        ks * 32 + quad * 8);
            c1[n] = __builtin_amdgcn_mfma_f32_16x16x32_bf16(a1[ks], b, c1[n], 0, 0, 0);
        }
    #pragma unroll
    for (int n = 0; n < 8; ++n)
        #pragma unroll
        for (int r = 0; r < 4; ++r)
            Y1s[wv * 16 + quad * 4 + r][n * 16 + ln] = f2b(gelu_f(c1[n][r]));

    // mlp2: 64x128 @ 128x64  (rows are wave-private; same-wave DS ordering)
    bf16x8 a2[4];
    #pragma unroll
    for (int ks = 0; ks < 4; ++ks)
        a2[ks] = *(const bf16x8*)&Y1s[wv * 16 + ln][ks * 32 + quad * 8];
    const ushort* W2h = w2t + (size_t)h * DKER * DHID;
    f32x4 c2[4];
    #pragma unroll
    for (int n = 0; n < 4; ++n) c2[n] = (f32x4){0.f, 0.f, 0.f, 0.f};
    #pragma unroll
    for (int n = 0; n < 4; ++n)
        #pragma unroll
        for (int ks = 0; ks < 4; ++ks) {
            bf16x8 b = *(const bf16x8*)(W2h + (size_t)(n * 16 + ln) * DHID +
                                        ks * 32 + quad * 8);
            c2[n] = __builtin_amdgcn_mfma_f32_16x16x32_bf16(a2[ks], b, c2[n], 0, 0, 0);
        }

    if (z == 0) {
        #pragma unroll
        for (int n = 0; n < 4; ++n)
            #pragma unroll
            for (int r = 0; r < 4; ++r)
                Q2[((size_t)h * S + s0 + wv * 16 + quad * 4 + r) * DKER + n * 16 + ln] =
                    f2b(fabsf(gelu_f(c2[n][r])));
        return;
    }

    // k path: k2 = |sD| * gelu; k3 = |k2 + (k2 @ Ik) * sD2|
    float k2v[4][4];
    float sdv[4], sd2v[4];
    #pragma unroll
    for (int n = 0; n < 4; ++n) {
        sdv[n]  = fabsf(sD[h * DKER + n * 16 + ln]);
        sd2v[n] = sD2[h * DKER + n * 16 + ln];
    }
    #pragma unroll
    for (int n = 0; n < 4; ++n)
        #pragma unroll
        for (int r = 0; r < 4; ++r) {
            k2v[n][r] = sdv[n] * gelu_f(c2[n][r]);
            K2s[wv * 16 + quad * 4 + r][n * 16 + ln] = f2b(k2v[n][r]);
        }
    bf16x8 a3[2];
    #pragma unroll
    for (int ks = 0; ks < 2; ++ks)
        a3[ks] = *(const bf16x8*)&K2s[wv * 16 + ln][ks * 32 + quad * 8];
    const ushort* Ikh = ikt + (size_t)h * DKER * DKER;
    f32x4 c3[4];
    #pragma unroll
    for (int n = 0; n < 4; ++n) c3[n] = (f32x4){0.f, 0.f, 0.f, 0.f};
    #pragma unroll
    for (int n = 0; n < 4; ++n)
        #pragma unroll
        for (int ks = 0; ks < 2; ++ks) {
            bf16x8 b = *(const bf16x8*)(Ikh + (size_t)(n * 16 + ln) * DKER +
                                        ks * 32 + quad * 8);
            c3[n] = __builtin_amdgcn_mfma_f32_16x16x32_bf16(a3[ks], b, c3[n], 0, 0, 0);
        }
    #pragma unroll
    for (int n = 0; n < 4; ++n)
        #pragma unroll
        for (int r = 0; r < 4; ++r)
            K3[((size_t)h * S + s0 + wv * 16 + quad * 4 + r) * DKER + n * 16 + ln] =
                f2b(fabsf(k2v[n][r] + c3[n][r] * sd2v[n]));
}

// ---- Vt[h][c][t] = bf16( V[t][h*128+c] ) ----
__global__ __launch_bounds__(256) void k_vt(const float* __restrict__ V,
                                            ushort* __restrict__ Vt) {
    const int h = blockIdx.y;
    const int t0 = blockIdx.x * 64;
    const int tid = threadIdx.x;
    __shared__ ushort Ls[128][72];
    #pragma unroll
    for (int it = 0; it < 8; ++it) {
        int idx = it * 256 + tid;
        int r = idx >> 5, c4 = idx & 31;
        float4 v = *(const float4*)(V + (size_t)(t0 + r) * DD + h * DH + c4 * 4);
        Ls[c4 * 4 + 0][r] = f2b(v.x);
        Ls[c4 * 4 + 1][r] = f2b(v.y);
        Ls[c4 * 4 + 2][r] = f2b(v.z);
        Ls[c4 * 4 + 3][r] = f2b(v.w);
    }
    __syncthreads();
    #pragma unroll
    for (int it = 0; it < 4; ++it) {
        int idx = it * 256 + tid;
        int row = idx >> 3, cc = idx & 7;
        *(bf16x8*)(Vt + ((size_t)h * DH + row) * S + t0 + cc * 8) =
            *(const bf16x8*)(&Ls[row][cc * 8]);
    }
}

// ---- pack mask bits ----
__global__ __launch_bounds__(256) void k_mpack(const int* __restrict__ mask,
                                               uint* __restrict__ pm) {
    const int gw = blockIdx.x * 4 + (threadIdx.x >> 6);
    const int lane = threadIdx.x & 63;
    const int row = gw >> 5;
    const int w64 = gw & 31;
    int mv = mask[(size_t)row * S + w64 * 64 + lane];
    unsigned long long b = __ballot(mv != 0);
    if (lane == 0)  pm[row * 64 + w64 * 2]     = (uint)b;
    if (lane == 32) pm[row * 64 + w64 * 2 + 1] = (uint)(b >> 32);
}

// ---- EV[h] = E_h @ V_h^T, E[s,t] = mask ? eps : exp(Wsp[h,s,t]) ----
// Barrier-free streaming GEMM: the 268 MB Wsp read happens exactly once, at
// full BW, with exp fused on the fly. No LDS; waves free-run. B operand comes
// from the pre-transposed Vt (L2-resident per head with the XCD swizzle).
__global__ __launch_bounds__(256, 4) void k_ev(const float* __restrict__ Wsp,
                                               const ushort* __restrict__ Vt,
                                               const uint* __restrict__ pm,
                                               float* __restrict__ EV) {
    const int bid = blockIdx.x;
    const int id = (bid & 7) * 64 + (bid >> 3);   // XCD-contiguous remap (512 = 8*64)
    const int h = id >> 5;
    const int s0 = (id & 31) * 64;
    const int tid = threadIdx.x;
    const int wv = tid >> 6, lane = tid & 63;
    const int ln = lane & 15, quad = lane >> 4;
    const int arow = s0 + wv * 16 + ln;           // A-fragment row (lane layout)

    const float*  Wr  = Wsp + (size_t)h * S * S + (size_t)arow * S;
    const uint*   pr  = pm + (size_t)arow * 64;
    const ushort* Vth = Vt + (size_t)h * DH * S;

    f32x4 O[8];
    #pragma unroll
    for (int v = 0; v < 8; ++v) O[v] = (f32x4){0.f, 0.f, 0.f, 0.f};

    for (int t0 = 0; t0 < S; t0 += 64) {
        uint2 mword = *(const uint2*)(pr + (t0 >> 5));
        bf16x8 a[2];
        #pragma unroll
        for (int ks = 0; ks < 2; ++ks) {
            const float* wp = Wr + t0 + ks * 32 + quad * 8;
            float4 w0 = *(const float4*)wp;
            float4 w1 = *(const float4*)(wp + 4);
            uint mb = (ks ? mword.y : mword.x) >> (quad * 8);
            float p[8];
            p[0] = w0.x; p[1] = w0.y; p[2] = w0.z; p[3] = w0.w;
            p[4] = w1.x; p[5] = w1.y; p[6] = w1.z; p[7] = w1.w;
            #pragma unroll
            for (int j = 0; j < 8; ++j)
                p[j] = ((mb >> j) & 1) ? EPSF : __expf(p[j]);
            a[ks] = pack8(make_float4(p[0], p[1], p[2], p[3]),
                          make_float4(p[4], p[5], p[6], p[7]));
        }
        #pragma unroll
        for (int ks = 0; ks < 2; ++ks)
            #pragma unroll
            for (int v = 0; v < 8; ++v) {
                bf16x8 vf = *(const bf16x8*)(Vth + (size_t)(v * 16 + ln) * S +
                                             t0 + ks * 32 + quad * 8);
                O[v] = __builtin_amdgcn_mfma_f32_16x16x32_bf16(a[ks], vf, O[v], 0, 0, 0);
            }
    }
    const int orow = s0 + wv * 16 + quad * 4;     // C/D layout row
    #pragma unroll
    for (int v = 0; v < 8; ++v)
        #pragma unroll
        for (int r = 0; r < 4; ++r)
            EV[((size_t)h * S + orow + r) * DH + v * 16 + ln] = O[v][r];
}

// ---- masked low-rank attention + EV merge ----
// No Wsp, no exp, no LDS staging, no barriers: K3 (256 KB/head) and Vt
// (512 KB/head) are L2-resident (XCD swizzle keeps 2 heads/XCD). Ps is the
// wave-private P-transpose buffer (same-wave DS ordering, no __syncthreads).
__global__ __launch_bounds__(256, 3) void k_attn(const ushort* __restrict__ Q2,
                                                 const ushort* __restrict__ K3,
                                                 const ushort* __restrict__ Vt,
                                                 const uint* __restrict__ pm,
                                                 const float* __restrict__ EV,
                                                 const float* __restrict__ lse,
                                                 float* __restrict__ out) {
    const int bid = blockIdx.x;
    const int id = (bid & 7) * 64 + (bid >> 3);   // XCD-contiguous remap
    const int h = id >> 5;
    const int s0 = (id & 31) * 64;
    const int tid = threadIdx.x;
    const int wv = tid >> 6, lane = tid & 63;
    const int ln = lane & 15, quad = lane >> 4;
    __shared__ ushort Ps[4][16][72];

    const ushort* K3h = K3 + (size_t)h * S * DKER;
    const ushort* Vth = Vt + (size_t)h * DH * S;
    const int srow_q = s0 + wv * 16 + quad * 4;
    const int arow = s0 + wv * 16 + ln;

    bf16x8 aq[2];
    #pragma unroll
    for (int ks = 0; ks < 2; ++ks)
        aq[ks] = *(const bf16x8*)(Q2 + ((size_t)h * S + arow) * DKER +
                                  ks * 32 + quad * 8);

    f32x4 O[8];
    #pragma unroll
    for (int v = 0; v < 8; ++v) O[v] = (f32x4){0.f, 0.f, 0.f, 0.f};
    float rs[4] = {0.f, 0.f, 0.f, 0.f};

    for (int t0 = 0; t0 < S; t0 += 64) {
        uint2 mw[4];
        #pragma unroll
        for (int r = 0; r < 4; ++r)
            mw[r] = *(const uint2*)(pm + (size_t)(srow_q + r) * 64 + (t0 >> 5));

        f32x4 sc[4];
        #pragma unroll
        for (int n = 0; n < 4; ++n) sc[n] = (f32x4){0.f, 0.f, 0.f, 0.f};
        #pragma unroll
        for (int ks = 0; ks < 2; ++ks)
            #pragma unroll
            for (int n = 0; n < 4; ++n) {
                bf16x8 bf = *(const bf16x8*)(K3h + (size_t)(t0 + n * 16 + ln) * DKER +
                                             ks * 32 + quad * 8);
                sc[n] = __builtin_amdgcn_mfma_f32_16x16x32_bf16(aq[ks], bf, sc[n], 0, 0, 0);
            }

        #pragma unroll
        for (int n = 0; n < 4; ++n)
            #pragma unroll
            for (int r = 0; r < 4; ++r) {
                uint word = (n >= 2) ? mw[r].y : mw[r].x;
                int m = (word >> (((n & 1) << 4) + ln)) & 1;
                float s = sc[n][r];
                float p = m ? s : 0.f;      // eps + exp(w) parts live in EV
                rs[r] += p;
                Ps[wv][quad * 4 + r][n * 16 + ln] = f2b(p);
            }

        #pragma unroll
        for (int ks = 0; ks < 2; ++ks) {
            bf16x8 pf = *(const bf16x8*)&Ps[wv][ln][ks * 32 + quad * 8];
            #pragma unroll
            for (int v = 0; v < 8; ++v) {
                bf16x8 vf = *(const bf16x8*)(Vth + (size_t)(v * 16 + ln) * S +
                                             t0 + ks * 32 + quad * 8);
                O[v] = __builtin_amdgcn_mfma_f32_16x16x32_bf16(pf, vf, O[v], 0, 0, 0);
            }
        }
    }

    // rowsum across the 16 lanes sharing each C/D row
    #pragma unroll
    for (int r = 0; r < 4; ++r) {
        float v = rs[r];
        v += __shfl_xor(v, 1); v += __shfl_xor(v, 2);
        v += __shfl_xor(v, 4); v += __shfl_xor(v, 8);
        rs[r] = v;
    }
    float idv[4];
    #pragma unroll
    for (int r = 0; r < 4; ++r)
        idv[r] = 1.f / (rs[r] + EPSF + expf(lse[(size_t)h * S + srow_q + r]));
    const float* EVh = EV + ((size_t)h * S + srow_q) * DH;
    #pragma unroll
    for (int v = 0; v < 8; ++v)
        #pragma unroll
        for (int r = 0; r < 4; ++r)
            out[(size_t)(srow_q + r) * DD + h * DH + v * 16 + ln] =
                (O[v][r] + EVh[r * DH + v * 16 + ln]) * idv[r];
}

extern "C" void kernel_launch(void* const* d_in, const int* in_sizes, int n_in,
                              void* d_out, int out_size, void* d_ws, size_t ws_size,
                              hipStream_t stream) {
    const float* q   = (const float*)d_in[0];
    const float* k   = (const float*)d_in[1];
    const float* v   = (const float*)d_in[2];
    const int*   msk = (const int*)d_in[3];
    const float* lse = (const float*)d_in[4];
    const float* spw = (const float*)d_in[5];
    const float* wq1 = (const float*)d_in[6];
    const float* wk1 = (const float*)d_in[7];
    const float* wq2 = (const float*)d_in[8];
    const float* wk2 = (const float*)d_in[9];
    const float* ik  = (const float*)d_in[10];
    const float* sD  = (const float*)d_in[11];
    const float* sD2 = (const float*)d_in[12];
    float* out = (float*)d_out;

    ushort* q2b  = (ushort*)d_ws;                          // 16*2048*64
    ushort* k3b  = q2b + (size_t)NH * S * DKER;            // 16*2048*64
    ushort* vt   = k3b + (size_t)NH * S * DKER;            // 16*128*2048
    uint*   pm   = (uint*)(vt + (size_t)NH * DH * S);      // 2048*64
    ushort* w1qt = (ushort*)(pm + (size_t)S * 64);         // 16*128*128
    ushort* w1kt = w1qt + (size_t)NH * DH * DHID;
    ushort* w2qt = w1kt + (size_t)NH * DH * DHID;          // 16*64*128
    ushort* w2kt = w2qt + (size_t)NH * DKER * DHID;
    ushort* ikt  = w2kt + (size_t)NH * DKER * DHID;        // 16*64*64
    float*  ev   = (float*)(ikt + (size_t)NH * DKER * DKER); // 16*2048*128 fp32

    dim3 g(S / 64, NH), b(256);
    k_wprep<<<dim3(NH, 5), b, 0, stream>>>(wq1, wk1, wq2, wk2, ik,
                                           w1qt, w1kt, w2qt, w2kt, ikt);
    k_mpack<<<dim3(S * 32 / 4), b, 0, stream>>>(msk, pm);
    k_vt<<<g, b, 0, stream>>>(v, vt);
    k_fused<<<dim3(S / 64, NH, 2), b, 0, stream>>>(q, k, w1qt, w1kt, w2qt, w2kt,
                                                   ikt, sD, sD2, q2b, k3b);
    k_ev<<<dim3(512), b, 0, stream>>>(spw, vt, pm, ev);
    k_attn<<<dim3(512), b, 0, stream>>>(q2b, k3b, vt, pm, ev, lse, out);
}

// Round 3
// 740.170 us; speedup vs baseline: 1.0090x; 1.0090x over previous
//
#include <hip/hip_runtime.h>
#include <math.h>

#define S 2048
#define DD 2048
#define NH 16
#define DH 128
#define DHID 128
#define DKER 64
#define EPSF 1e-6f

typedef __attribute__((ext_vector_type(8))) short bf16x8;
typedef __attribute__((ext_vector_type(4))) float f32x4;

__device__ __forceinline__ float gelu_f(float x) {
    return 0.5f * x * (1.0f + erff(x * 0.7071067811865475f));
}

__device__ __forceinline__ ushort f2b(float x) {
    uint32_t u = __float_as_uint(x);
    uint32_t r = (u + 0x7FFFu + ((u >> 16) & 1u)) >> 16;
    return (ushort)r;
}

__device__ __forceinline__ bf16x8 pack8(float4 a, float4 b) {
    bf16x8 r;
    r[0] = (short)f2b(a.x); r[1] = (short)f2b(a.y);
    r[2] = (short)f2b(a.z); r[3] = (short)f2b(a.w);
    r[4] = (short)f2b(b.x); r[5] = (short)f2b(b.y);
    r[6] = (short)f2b(b.z); r[7] = (short)f2b(b.w);
    return r;
}

// ---- weight prep: transpose+convert to bf16 [out_dim][in_dim] ----
__global__ __launch_bounds__(256) void k_wprep(const float* __restrict__ wq1,
                                               const float* __restrict__ wk1,
                                               const float* __restrict__ wq2,
                                               const float* __restrict__ wk2,
                                               const float* __restrict__ ik,
                                               ushort* __restrict__ w1qt,
                                               ushort* __restrict__ w1kt,
                                               ushort* __restrict__ w2qt,
                                               ushort* __restrict__ w2kt,
                                               ushort* __restrict__ ikt) {
    const int h = blockIdx.x, m = blockIdx.y, tid = threadIdx.x;
    const float* src; ushort* dst; int D;
    if (m == 0)      { src = wq1 + h * 16384; dst = w1qt + h * 16384; D = 128; }
    else if (m == 1) { src = wk1 + h * 16384; dst = w1kt + h * 16384; D = 128; }
    else if (m == 2) { src = wq2 + h * 8192;  dst = w2qt + h * 8192;  D = 128; }
    else if (m == 3) { src = wk2 + h * 8192;  dst = w2kt + h * 8192;  D = 128; }
    else             { src = ik  + h * 4096;  dst = ikt  + h * 4096;  D = 64;  }
    const int E = (m == 0 || m == 1) ? 128 : 64;
    const int dsh = (D == 128) ? 7 : 6;
    const int n = E * D;
    for (int idx = tid; idx < n; idx += 256) {
        int e = idx >> dsh, d = idx & (D - 1);
        dst[idx] = f2b(src[d * E + e]);
    }
}

// ---- fused MLP paths: z=0 -> Q2abs, z=1 -> K3abs ----
// B-fragment loads batched per-ks (8 resp. 4 independent loads in flight)
__global__ __launch_bounds__(256) void k_fused(const float* __restrict__ Xq,
                                               const float* __restrict__ Xk,
                                               const ushort* __restrict__ w1qt,
                                               const ushort* __restrict__ w1kt,
                                               const ushort* __restrict__ w2qt,
                                               const ushort* __restrict__ w2kt,
                                               const ushort* __restrict__ ikt,
                                               const float* __restrict__ sD,
                                               const float* __restrict__ sD2,
                                               ushort* __restrict__ Q2,
                                               ushort* __restrict__ K3) {
    const int h = blockIdx.y;
    const int s0 = blockIdx.x * 64;
    const int z = blockIdx.z;
    const int tid = threadIdx.x;
    const int wv = tid >> 6, lane = tid & 63;
    const int ln = lane & 15, quad = lane >> 4;
    __shared__ ushort Y1s[64][136];   // 272B row ≡ 4 dw mod 32 banks
    __shared__ ushort K2s[64][72];

    const float* X = z ? Xk : Xq;
    const ushort* w1t = z ? w1kt : w1qt;
    const ushort* w2t = z ? w2kt : w2qt;

    // A1: X rows (fp32 -> bf16), direct from global
    const float* Xr = X + (size_t)(s0 + wv * 16 + ln) * DD + h * DH;
    bf16x8 a1[4];
    #pragma unroll
    for (int ks = 0; ks < 4; ++ks)
        a1[ks] = pack8(*(const float4*)(Xr + ks * 32 + quad * 8),
                       *(const float4*)(Xr + ks * 32 + quad * 8 + 4));

    // mlp1: 64x128 @ 128x128
    const ushort* W1h = w1t + (size_t)h * DH * DHID;
    f32x4 c1[8];
    #pragma unroll
    for (int n = 0; n < 8; ++n) c1[n] = (f32x4){0.f, 0.f, 0.f, 0.f};
    #pragma unroll
    for (int ks = 0; ks < 4; ++ks) {
        bf16x8 bb[8];
        #pragma unroll
        for (int n = 0; n < 8; ++n)
            bb[n] = *(const bf16x8*)(W1h + (size_t)(n * 16 + ln) * DHID +
                                     ks * 32 + quad * 8);
        #pragma unroll
        for (int n = 0; n < 8; ++n)
            c1[n] = __builtin_amdgcn_mfma_f32_16x16x32_bf16(a1[ks], bb[n], c1[n], 0, 0, 0);
    }
    #pragma unroll
    for (int n = 0; n < 8; ++n)
        #pragma unroll
        for (int r = 0; r < 4; ++r)
            Y1s[wv * 16 + quad * 4 + r][n * 16 + ln] = f2b(gelu_f(c1[n][r]));

    // mlp2: 64x128 @ 128x64  (rows are wave-private; same-wave DS ordering)
    bf16x8 a2[4];
    #pragma unroll
    for (int ks = 0; ks < 4; ++ks)
        a2[ks] = *(const bf16x8*)&Y1s[wv * 16 + ln][ks * 32 + quad * 8];
    const ushort* W2h = w2t + (size_t)h * DKER * DHID;
    f32x4 c2[4];
    #pragma unroll
    for (int n = 0; n < 4; ++n) c2[n] = (f32x4){0.f, 0.f, 0.f, 0.f};
    #pragma unroll
    for (int ks = 0; ks < 4; ++ks) {
        bf16x8 bb[4];
        #pragma unroll
        for (int n = 0; n < 4; ++n)
            bb[n] = *(const bf16x8*)(W2h + (size_t)(n * 16 + ln) * DHID +
                                     ks * 32 + quad * 8);
        #pragma unroll
        for (int n = 0; n < 4; ++n)
            c2[n] = __builtin_amdgcn_mfma_f32_16x16x32_bf16(a2[ks], bb[n], c2[n], 0, 0, 0);
    }

    if (z == 0) {
        #pragma unroll
        for (int n = 0; n < 4; ++n)
            #pragma unroll
            for (int r = 0; r < 4; ++r)
                Q2[((size_t)h * S + s0 + wv * 16 + quad * 4 + r) * DKER + n * 16 + ln] =
                    f2b(fabsf(gelu_f(c2[n][r])));
        return;
    }

    // k path: k2 = |sD| * gelu; k3 = |k2 + (k2 @ Ik) * sD2|
    float k2v[4][4];
    float sdv[4], sd2v[4];
    #pragma unroll
    for (int n = 0; n < 4; ++n) {
        sdv[n]  = fabsf(sD[h * DKER + n * 16 + ln]);
        sd2v[n] = sD2[h * DKER + n * 16 + ln];
    }
    #pragma unroll
    for (int n = 0; n < 4; ++n)
        #pragma unroll
        for (int r = 0; r < 4; ++r) {
            k2v[n][r] = sdv[n] * gelu_f(c2[n][r]);
            K2s[wv * 16 + quad * 4 + r][n * 16 + ln] = f2b(k2v[n][r]);
        }
    bf16x8 a3[2];
    #pragma unroll
    for (int ks = 0; ks < 2; ++ks)
        a3[ks] = *(const bf16x8*)&K2s[wv * 16 + ln][ks * 32 + quad * 8];
    const ushort* Ikh = ikt + (size_t)h * DKER * DKER;
    f32x4 c3[4];
    #pragma unroll
    for (int n = 0; n < 4; ++n) c3[n] = (f32x4){0.f, 0.f, 0.f, 0.f};
    #pragma unroll
    for (int ks = 0; ks < 2; ++ks) {
        bf16x8 bb[4];
        #pragma unroll
        for (int n = 0; n < 4; ++n)
            bb[n] = *(const bf16x8*)(Ikh + (size_t)(n * 16 + ln) * DKER +
                                     ks * 32 + quad * 8);
        #pragma unroll
        for (int n = 0; n < 4; ++n)
            c3[n] = __builtin_amdgcn_mfma_f32_16x16x32_bf16(a3[ks], bb[n], c3[n], 0, 0, 0);
    }
    #pragma unroll
    for (int n = 0; n < 4; ++n)
        #pragma unroll
        for (int r = 0; r < 4; ++r)
            K3[((size_t)h * S + s0 + wv * 16 + quad * 4 + r) * DKER + n * 16 + ln] =
                f2b(fabsf(k2v[n][r] + c3[n][r] * sd2v[n]));
}

// ---- Vt[h][c][t] = bf16( V[t][h*128+c] ) ----
__global__ __launch_bounds__(256) void k_vt(const float* __restrict__ V,
                                            ushort* __restrict__ Vt) {
    const int h = blockIdx.y;
    const int t0 = blockIdx.x * 64;
    const int tid = threadIdx.x;
    __shared__ ushort Ls[128][72];
    #pragma unroll
    for (int it = 0; it < 8; ++it) {
        int idx = it * 256 + tid;
        int r = idx >> 5, c4 = idx & 31;
        float4 v = *(const float4*)(V + (size_t)(t0 + r) * DD + h * DH + c4 * 4);
        Ls[c4 * 4 + 0][r] = f2b(v.x);
        Ls[c4 * 4 + 1][r] = f2b(v.y);
        Ls[c4 * 4 + 2][r] = f2b(v.z);
        Ls[c4 * 4 + 3][r] = f2b(v.w);
    }
    __syncthreads();
    #pragma unroll
    for (int it = 0; it < 4; ++it) {
        int idx = it * 256 + tid;
        int row = idx >> 3, cc = idx & 7;
        *(bf16x8*)(Vt + ((size_t)h * DH + row) * S + t0 + cc * 8) =
            *(const bf16x8*)(&Ls[row][cc * 8]);
    }
}

// ---- pack mask bits ----
__global__ __launch_bounds__(256) void k_mpack(const int* __restrict__ mask,
                                               uint* __restrict__ pm) {
    const int gw = blockIdx.x * 4 + (threadIdx.x >> 6);
    const int lane = threadIdx.x & 63;
    const int row = gw >> 5;
    const int w64 = gw & 31;
    int mv = mask[(size_t)row * S + w64 * 64 + lane];
    unsigned long long b = __ballot(mv != 0);
    if (lane == 0)  pm[row * 64 + w64 * 2]     = (uint)b;
    if (lane == 32) pm[row * 64 + w64 * 2 + 1] = (uint)(b >> 32);
}

// ---- EV[h] = E_h @ V_h^T, E[s,t] = mask ? eps : exp(Wsp[h,s,t]) ----
// Batched loads + 1-deep Wsp register prefetch: all 16 Vt (L2) loads and the
// next tile's 4 Wsp (HBM) loads are in flight while exp/pack/MFMA of the
// current tile runs. No LDS, no barriers.
__global__ __launch_bounds__(256, 2) void k_ev(const float* __restrict__ Wsp,
                                               const ushort* __restrict__ Vt,
                                               const uint* __restrict__ pm,
                                               float* __restrict__ EV) {
    const int bid = blockIdx.x;
    const int id = (bid & 7) * 64 + (bid >> 3);   // XCD-contiguous remap (512 = 8*64)
    const int h = id >> 5;
    const int s0 = (id & 31) * 64;
    const int tid = threadIdx.x;
    const int wv = tid >> 6, lane = tid & 63;
    const int ln = lane & 15, quad = lane >> 4;
    const int arow = s0 + wv * 16 + ln;           // A-fragment row (lane layout)

    const float*  Wr  = Wsp + (size_t)h * S * S + (size_t)arow * S;
    const uint*   pr  = pm + (size_t)arow * 64;
    const ushort* Vth = Vt + (size_t)h * DH * S;

    f32x4 O[8];
    #pragma unroll
    for (int v = 0; v < 8; ++v) O[v] = (f32x4){0.f, 0.f, 0.f, 0.f};

    // prefetch tile 0 Wsp + mask
    float4 cwa0, cwa1, cwb0, cwb1;
    uint2 cmw;
    {
        const float* wp = Wr + quad * 8;
        cwa0 = *(const float4*)wp;        cwa1 = *(const float4*)(wp + 4);
        cwb0 = *(const float4*)(wp + 32); cwb1 = *(const float4*)(wp + 36);
        cmw  = *(const uint2*)pr;
    }

    for (int t0 = 0; t0 < S; t0 += 64) {
        // batched Vt fragment loads for this tile (16 independent, L2)
        bf16x8 vf0[8], vf1[8];
        #pragma unroll
        for (int v = 0; v < 8; ++v) {
            const ushort* vp = Vth + (size_t)(v * 16 + ln) * S + t0 + quad * 8;
            vf0[v] = *(const bf16x8*)vp;
            vf1[v] = *(const bf16x8*)(vp + 32);
        }
        // prefetch next tile's Wsp (HBM) — consumed next iteration
        float4 nwa0, nwa1, nwb0, nwb1;
        uint2 nmw;
        if (t0 + 64 < S) {
            const float* wp = Wr + t0 + 64 + quad * 8;
            nwa0 = *(const float4*)wp;        nwa1 = *(const float4*)(wp + 4);
            nwb0 = *(const float4*)(wp + 32); nwb1 = *(const float4*)(wp + 36);
            nmw  = *(const uint2*)(pr + ((t0 + 64) >> 5));
        }
        // E = mask ? eps : exp(w), packed to bf16 A-fragments
        uint mb0 = cmw.x >> (quad * 8);
        uint mb1 = cmw.y >> (quad * 8);
        float p[8];
        p[0] = cwa0.x; p[1] = cwa0.y; p[2] = cwa0.z; p[3] = cwa0.w;
        p[4] = cwa1.x; p[5] = cwa1.y; p[6] = cwa1.z; p[7] = cwa1.w;
        #pragma unroll
        for (int j = 0; j < 8; ++j)
            p[j] = ((mb0 >> j) & 1) ? EPSF : __expf(p[j]);
        bf16x8 a0 = pack8(make_float4(p[0], p[1], p[2], p[3]),
                          make_float4(p[4], p[5], p[6], p[7]));
        p[0] = cwb0.x; p[1] = cwb0.y; p[2] = cwb0.z; p[3] = cwb0.w;
        p[4] = cwb1.x; p[5] = cwb1.y; p[6] = cwb1.z; p[7] = cwb1.w;
        #pragma unroll
        for (int j = 0; j < 8; ++j)
            p[j] = ((mb1 >> j) & 1) ? EPSF : __expf(p[j]);
        bf16x8 a1 = pack8(make_float4(p[0], p[1], p[2], p[3]),
                          make_float4(p[4], p[5], p[6], p[7]));
        #pragma unroll
        for (int v = 0; v < 8; ++v)
            O[v] = __builtin_amdgcn_mfma_f32_16x16x32_bf16(a0, vf0[v], O[v], 0, 0, 0);
        #pragma unroll
        for (int v = 0; v < 8; ++v)
            O[v] = __builtin_amdgcn_mfma_f32_16x16x32_bf16(a1, vf1[v], O[v], 0, 0, 0);
        cwa0 = nwa0; cwa1 = nwa1; cwb0 = nwb0; cwb1 = nwb1; cmw = nmw;
    }
    const int orow = s0 + wv * 16 + quad * 4;     // C/D layout row
    #pragma unroll
    for (int v = 0; v < 8; ++v)
        #pragma unroll
        for (int r = 0; r < 4; ++r)
            EV[((size_t)h * S + orow + r) * DH + v * 16 + ln] = O[v][r];
}

// ---- masked low-rank attention + EV merge ----
// All K3/Vt fragment loads batched up-front per tile (24 independent L2 loads
// in flight), then QK -> mask/Ps -> PV. No barriers; Ps is wave-private.
__global__ __launch_bounds__(256, 2) void k_attn(const ushort* __restrict__ Q2,
                                                 const ushort* __restrict__ K3,
                                                 const ushort* __restrict__ Vt,
                                                 const uint* __restrict__ pm,
                                                 const float* __restrict__ EV,
                                                 const float* __restrict__ lse,
                                                 float* __restrict__ out) {
    const int bid = blockIdx.x;
    const int id = (bid & 7) * 64 + (bid >> 3);   // XCD-contiguous remap
    const int h = id >> 5;
    const int s0 = (id & 31) * 64;
    const int tid = threadIdx.x;
    const int wv = tid >> 6, lane = tid & 63;
    const int ln = lane & 15, quad = lane >> 4;
    __shared__ ushort Ps[4][16][72];

    const ushort* K3h = K3 + (size_t)h * S * DKER;
    const ushort* Vth = Vt + (size_t)h * DH * S;
    const int srow_q = s0 + wv * 16 + quad * 4;
    const int arow = s0 + wv * 16 + ln;

    bf16x8 aq[2];
    #pragma unroll
    for (int ks = 0; ks < 2; ++ks)
        aq[ks] = *(const bf16x8*)(Q2 + ((size_t)h * S + arow) * DKER +
                                  ks * 32 + quad * 8);

    f32x4 O[8];
    #pragma unroll
    for (int v = 0; v < 8; ++v) O[v] = (f32x4){0.f, 0.f, 0.f, 0.f};
    float rs[4] = {0.f, 0.f, 0.f, 0.f};

    for (int t0 = 0; t0 < S; t0 += 64) {
        // batched loads: K3 B-fragments (8), Vt fragments (16), mask (4)
        bf16x8 bk[2][4];
        #pragma unroll
        for (int ks = 0; ks < 2; ++ks)
            #pragma unroll
            for (int n = 0; n < 4; ++n)
                bk[ks][n] = *(const bf16x8*)(K3h + (size_t)(t0 + n * 16 + ln) * DKER +
                                             ks * 32 + quad * 8);
        bf16x8 vf[2][8];
        #pragma unroll
        for (int ks = 0; ks < 2; ++ks)
            #pragma unroll
            for (int v = 0; v < 8; ++v)
                vf[ks][v] = *(const bf16x8*)(Vth + (size_t)(v * 16 + ln) * S +
                                             t0 + ks * 32 + quad * 8);
        uint2 mw[4];
        #pragma unroll
        for (int r = 0; r < 4; ++r)
            mw[r] = *(const uint2*)(pm + (size_t)(srow_q + r) * 64 + (t0 >> 5));

        f32x4 sc[4];
        #pragma unroll
        for (int n = 0; n < 4; ++n) sc[n] = (f32x4){0.f, 0.f, 0.f, 0.f};
        #pragma unroll
        for (int ks = 0; ks < 2; ++ks)
            #pragma unroll
            for (int n = 0; n < 4; ++n)
                sc[n] = __builtin_amdgcn_mfma_f32_16x16x32_bf16(aq[ks], bk[ks][n],
                                                                sc[n], 0, 0, 0);

        #pragma unroll
        for (int n = 0; n < 4; ++n)
            #pragma unroll
            for (int r = 0; r < 4; ++r) {
                uint word = (n >= 2) ? mw[r].y : mw[r].x;
                int m = (word >> (((n & 1) << 4) + ln)) & 1;
                float s = sc[n][r];
                float p = m ? s : 0.f;      // eps + exp(w) parts live in EV
                rs[r] += p;
                Ps[wv][quad * 4 + r][n * 16 + ln] = f2b(p);
            }

        #pragma unroll
        for (int ks = 0; ks < 2; ++ks) {
            bf16x8 pf = *(const bf16x8*)&Ps[wv][ln][ks * 32 + quad * 8];
            #pragma unroll
            for (int v = 0; v < 8; ++v)
                O[v] = __builtin_amdgcn_mfma_f32_16x16x32_bf16(pf, vf[ks][v], O[v],
                                                               0, 0, 0);
        }
    }

    // rowsum across the 16 lanes sharing each C/D row
    #pragma unroll
    for (int r = 0; r < 4; ++r) {
        float v = rs[r];
        v += __shfl_xor(v, 1); v += __shfl_xor(v, 2);
        v += __shfl_xor(v, 4); v += __shfl_xor(v, 8);
        rs[r] = v;
    }
    float idv[4];
    #pragma unroll
    for (int r = 0; r < 4; ++r)
        idv[r] = 1.f / (rs[r] + EPSF + expf(lse[(size_t)h * S + srow_q + r]));
    const float* EVh = EV + ((size_t)h * S + srow_q) * DH;
    #pragma unroll
    for (int v = 0; v < 8; ++v)
        #pragma unroll
        for (int r = 0; r < 4; ++r)
            out[(size_t)(srow_q + r) * DD + h * DH + v * 16 + ln] =
                (O[v][r] + EVh[r * DH + v * 16 + ln]) * idv[r];
}

extern "C" void kernel_launch(void* const* d_in, const int* in_sizes, int n_in,
                              void* d_out, int out_size, void* d_ws, size_t ws_size,
                              hipStream_t stream) {
    const float* q   = (const float*)d_in[0];
    const float* k   = (const float*)d_in[1];
    const float* v   = (const float*)d_in[2];
    const int*   msk = (const int*)d_in[3];
    const float* lse = (const float*)d_in[4];
    const float* spw = (const float*)d_in[5];
    const float* wq1 = (const float*)d_in[6];
    const float* wk1 = (const float*)d_in[7];
    const float* wq2 = (const float*)d_in[8];
    const float* wk2 = (const float*)d_in[9];
    const float* ik  = (const float*)d_in[10];
    const float* sD  = (const float*)d_in[11];
    const float* sD2 = (const float*)d_in[12];
    float* out = (float*)d_out;

    ushort* q2b  = (ushort*)d_ws;                          // 16*2048*64
    ushort* k3b  = q2b + (size_t)NH * S * DKER;            // 16*2048*64
    ushort* vt   = k3b + (size_t)NH * S * DKER;            // 16*128*2048
    uint*   pm   = (uint*)(vt + (size_t)NH * DH * S);      // 2048*64
    ushort* w1qt = (ushort*)(pm + (size_t)S * 64);         // 16*128*128
    ushort* w1kt = w1qt + (size_t)NH * DH * DHID;
    ushort* w2qt = w1kt + (size_t)NH * DH * DHID;          // 16*64*128
    ushort* w2kt = w2qt + (size_t)NH * DKER * DHID;
    ushort* ikt  = w2kt + (size_t)NH * DKER * DHID;        // 16*64*64
    float*  ev   = (float*)(ikt + (size_t)NH * DKER * DKER); // 16*2048*128 fp32

    dim3 g(S / 64, NH), b(256);
    k_wprep<<<dim3(NH, 5), b, 0, stream>>>(wq1, wk1, wq2, wk2, ik,
                                           w1qt, w1kt, w2qt, w2kt, ikt);
    k_mpack<<<dim3(S * 32 / 4), b, 0, stream>>>(msk, pm);
    k_vt<<<g, b, 0, stream>>>(v, vt);
    k_fused<<<dim3(S / 64, NH, 2), b, 0, stream>>>(q, k, w1qt, w1kt, w2qt, w2kt,
                                                   ikt, sD, sD2, q2b, k3b);
    k_ev<<<dim3(512), b, 0, stream>>>(spw, vt, pm, ev);
    k_attn<<<dim3(512), b, 0, stream>>>(q2b, k3b, vt, pm, ev, lse, out);
}

// Round 4
// 501.704 us; speedup vs baseline: 1.4887x; 1.4753x over previous
//
#include <hip/hip_runtime.h>
#include <math.h>

#define S 2048
#define DD 2048
#define NH 16
#define DH 128
#define DHID 128
#define DKER 64
#define EPSF 1e-6f

typedef __attribute__((ext_vector_type(8))) short bf16x8;
typedef __attribute__((ext_vector_type(4))) float f32x4;

__device__ __forceinline__ float gelu_f(float x) {
    return 0.5f * x * (1.0f + erff(x * 0.7071067811865475f));
}

__device__ __forceinline__ ushort f2b(float x) {
    uint32_t u = __float_as_uint(x);
    uint32_t r = (u + 0x7FFFu + ((u >> 16) & 1u)) >> 16;
    return (ushort)r;
}

__device__ __forceinline__ bf16x8 pack8(float4 a, float4 b) {
    bf16x8 r;
    r[0] = (short)f2b(a.x); r[1] = (short)f2b(a.y);
    r[2] = (short)f2b(a.z); r[3] = (short)f2b(a.w);
    r[4] = (short)f2b(b.x); r[5] = (short)f2b(b.y);
    r[6] = (short)f2b(b.z); r[7] = (short)f2b(b.w);
    return r;
}

// merge LR score (bf16, A-layout) with sparse exp(w) under mask bits
__device__ __forceinline__ bf16x8 merge8(bf16x8 ps, uint mb, float4 wa, float4 wb) {
    float w[8] = {wa.x, wa.y, wa.z, wa.w, wb.x, wb.y, wb.z, wb.w};
    float p[8];
    #pragma unroll
    for (int j = 0; j < 8; ++j) {
        float sv = __uint_as_float(((uint)(ushort)ps[j]) << 16);
        p[j] = ((mb >> j) & 1) ? (sv + EPSF) : __expf(w[j]);
    }
    return pack8(make_float4(p[0], p[1], p[2], p[3]),
                 make_float4(p[4], p[5], p[6], p[7]));
}

// ---- weight prep: transpose+convert to bf16 [out_dim][in_dim] ----
__global__ __launch_bounds__(256) void k_wprep(const float* __restrict__ wq1,
                                               const float* __restrict__ wk1,
                                               const float* __restrict__ wq2,
                                               const float* __restrict__ wk2,
                                               const float* __restrict__ ik,
                                               ushort* __restrict__ w1qt,
                                               ushort* __restrict__ w1kt,
                                               ushort* __restrict__ w2qt,
                                               ushort* __restrict__ w2kt,
                                               ushort* __restrict__ ikt) {
    const int h = blockIdx.x, m = blockIdx.y, tid = threadIdx.x;
    const float* src; ushort* dst; int D;
    if (m == 0)      { src = wq1 + h * 16384; dst = w1qt + h * 16384; D = 128; }
    else if (m == 1) { src = wk1 + h * 16384; dst = w1kt + h * 16384; D = 128; }
    else if (m == 2) { src = wq2 + h * 8192;  dst = w2qt + h * 8192;  D = 128; }
    else if (m == 3) { src = wk2 + h * 8192;  dst = w2kt + h * 8192;  D = 128; }
    else             { src = ik  + h * 4096;  dst = ikt  + h * 4096;  D = 64;  }
    const int E = (m == 0 || m == 1) ? 128 : 64;
    const int dsh = (D == 128) ? 7 : 6;
    const int n = E * D;
    for (int idx = tid; idx < n; idx += 256) {
        int e = idx >> dsh, d = idx & (D - 1);
        dst[idx] = f2b(src[d * E + e]);
    }
}

// ---- fused MLP paths: z=0 -> Q2abs, z=1 -> K3abs ----
__global__ __launch_bounds__(256) void k_fused(const float* __restrict__ Xq,
                                               const float* __restrict__ Xk,
                                               const ushort* __restrict__ w1qt,
                                               const ushort* __restrict__ w1kt,
                                               const ushort* __restrict__ w2qt,
                                               const ushort* __restrict__ w2kt,
                                               const ushort* __restrict__ ikt,
                                               const float* __restrict__ sD,
                                               const float* __restrict__ sD2,
                                               ushort* __restrict__ Q2,
                                               ushort* __restrict__ K3) {
    const int h = blockIdx.y;
    const int s0 = blockIdx.x * 64;
    const int z = blockIdx.z;
    const int tid = threadIdx.x;
    const int wv = tid >> 6, lane = tid & 63;
    const int ln = lane & 15, quad = lane >> 4;
    __shared__ ushort Y1s[64][136];   // 272B row ≡ 4 dw mod 32 banks
    __shared__ ushort K2s[64][72];

    const float* X = z ? Xk : Xq;
    const ushort* w1t = z ? w1kt : w1qt;
    const ushort* w2t = z ? w2kt : w2qt;

    // A1: X rows (fp32 -> bf16), direct from global
    const float* Xr = X + (size_t)(s0 + wv * 16 + ln) * DD + h * DH;
    bf16x8 a1[4];
    #pragma unroll
    for (int ks = 0; ks < 4; ++ks)
        a1[ks] = pack8(*(const float4*)(Xr + ks * 32 + quad * 8),
                       *(const float4*)(Xr + ks * 32 + quad * 8 + 4));

    // mlp1: 64x128 @ 128x128
    const ushort* W1h = w1t + (size_t)h * DH * DHID;
    f32x4 c1[8];
    #pragma unroll
    for (int n = 0; n < 8; ++n) c1[n] = (f32x4){0.f, 0.f, 0.f, 0.f};
    #pragma unroll
    for (int ks = 0; ks < 4; ++ks) {
        bf16x8 bb[8];
        #pragma unroll
        for (int n = 0; n < 8; ++n)
            bb[n] = *(const bf16x8*)(W1h + (size_t)(n * 16 + ln) * DHID +
                                     ks * 32 + quad * 8);
        #pragma unroll
        for (int n = 0; n < 8; ++n)
            c1[n] = __builtin_amdgcn_mfma_f32_16x16x32_bf16(a1[ks], bb[n], c1[n], 0, 0, 0);
    }
    #pragma unroll
    for (int n = 0; n < 8; ++n)
        #pragma unroll
        for (int r = 0; r < 4; ++r)
            Y1s[wv * 16 + quad * 4 + r][n * 16 + ln] = f2b(gelu_f(c1[n][r]));

    // mlp2: 64x128 @ 128x64  (rows are wave-private; same-wave DS ordering)
    bf16x8 a2[4];
    #pragma unroll
    for (int ks = 0; ks < 4; ++ks)
        a2[ks] = *(const bf16x8*)&Y1s[wv * 16 + ln][ks * 32 + quad * 8];
    const ushort* W2h = w2t + (size_t)h * DKER * DHID;
    f32x4 c2[4];
    #pragma unroll
    for (int n = 0; n < 4; ++n) c2[n] = (f32x4){0.f, 0.f, 0.f, 0.f};
    #pragma unroll
    for (int ks = 0; ks < 4; ++ks) {
        bf16x8 bb[4];
        #pragma unroll
        for (int n = 0; n < 4; ++n)
            bb[n] = *(const bf16x8*)(W2h + (size_t)(n * 16 + ln) * DHID +
                                     ks * 32 + quad * 8);
        #pragma unroll
        for (int n = 0; n < 4; ++n)
            c2[n] = __builtin_amdgcn_mfma_f32_16x16x32_bf16(a2[ks], bb[n], c2[n], 0, 0, 0);
    }

    if (z == 0) {
        #pragma unroll
        for (int n = 0; n < 4; ++n)
            #pragma unroll
            for (int r = 0; r < 4; ++r)
                Q2[((size_t)h * S + s0 + wv * 16 + quad * 4 + r) * DKER + n * 16 + ln] =
                    f2b(fabsf(gelu_f(c2[n][r])));
        return;
    }

    // k path: k2 = |sD| * gelu; k3 = |k2 + (k2 @ Ik) * sD2|
    float k2v[4][4];
    float sdv[4], sd2v[4];
    #pragma unroll
    for (int n = 0; n < 4; ++n) {
        sdv[n]  = fabsf(sD[h * DKER + n * 16 + ln]);
        sd2v[n] = sD2[h * DKER + n * 16 + ln];
    }
    #pragma unroll
    for (int n = 0; n < 4; ++n)
        #pragma unroll
        for (int r = 0; r < 4; ++r) {
            k2v[n][r] = sdv[n] * gelu_f(c2[n][r]);
            K2s[wv * 16 + quad * 4 + r][n * 16 + ln] = f2b(k2v[n][r]);
        }
    bf16x8 a3[2];
    #pragma unroll
    for (int ks = 0; ks < 2; ++ks)
        a3[ks] = *(const bf16x8*)&K2s[wv * 16 + ln][ks * 32 + quad * 8];
    const ushort* Ikh = ikt + (size_t)h * DKER * DKER;
    f32x4 c3[4];
    #pragma unroll
    for (int n = 0; n < 4; ++n) c3[n] = (f32x4){0.f, 0.f, 0.f, 0.f};
    #pragma unroll
    for (int ks = 0; ks < 2; ++ks) {
        bf16x8 bb[4];
        #pragma unroll
        for (int n = 0; n < 4; ++n)
            bb[n] = *(const bf16x8*)(Ikh + (size_t)(n * 16 + ln) * DKER +
                                     ks * 32 + quad * 8);
        #pragma unroll
        for (int n = 0; n < 4; ++n)
            c3[n] = __builtin_amdgcn_mfma_f32_16x16x32_bf16(a3[ks], bb[n], c3[n], 0, 0, 0);
    }
    #pragma unroll
    for (int n = 0; n < 4; ++n)
        #pragma unroll
        for (int r = 0; r < 4; ++r)
            K3[((size_t)h * S + s0 + wv * 16 + quad * 4 + r) * DKER + n * 16 + ln] =
                f2b(fabsf(k2v[n][r] + c3[n][r] * sd2v[n]));
}

// ---- Vt[h][c][t] = bf16( V[t][h*128+c] ) ----
__global__ __launch_bounds__(256) void k_vt(const float* __restrict__ V,
                                            ushort* __restrict__ Vt) {
    const int h = blockIdx.y;
    const int t0 = blockIdx.x * 64;
    const int tid = threadIdx.x;
    __shared__ ushort Ls[128][72];
    #pragma unroll
    for (int it = 0; it < 8; ++it) {
        int idx = it * 256 + tid;
        int r = idx >> 5, c4 = idx & 31;
        float4 v = *(const float4*)(V + (size_t)(t0 + r) * DD + h * DH + c4 * 4);
        Ls[c4 * 4 + 0][r] = f2b(v.x);
        Ls[c4 * 4 + 1][r] = f2b(v.y);
        Ls[c4 * 4 + 2][r] = f2b(v.z);
        Ls[c4 * 4 + 3][r] = f2b(v.w);
    }
    __syncthreads();
    #pragma unroll
    for (int it = 0; it < 4; ++it) {
        int idx = it * 256 + tid;
        int row = idx >> 3, cc = idx & 7;
        *(bf16x8*)(Vt + ((size_t)h * DH + row) * S + t0 + cc * 8) =
            *(const bf16x8*)(&Ls[row][cc * 8]);
    }
}

// ---- pack mask bits ----
__global__ __launch_bounds__(256) void k_mpack(const int* __restrict__ mask,
                                               uint* __restrict__ pm) {
    const int gw = blockIdx.x * 4 + (threadIdx.x >> 6);
    const int lane = threadIdx.x & 63;
    const int row = gw >> 5;
    const int w64 = gw & 31;
    int mv = mask[(size_t)row * S + w64 * 64 + lane];
    unsigned long long b = __ballot(mv != 0);
    if (lane == 0)  pm[row * 64 + w64 * 2]     = (uint)b;
    if (lane == 32) pm[row * 64 + w64 * 2 + 1] = (uint)(b >> 32);
}

// ---- fused attention: merged P = mask ? s_lr+eps : exp(w), one PV pass ----
// K3/Vt staged through LDS with 1-iteration register prefetch (round-0 proven
// structure). Wsp loaded in A-fragment layout (4x float4/thread) with a 2-deep
// cross-iteration register prefetch so its HBM latency (~900cy) hides under
// ~2 full compute iterations. LR scores transpose C/D -> A layout through Ps;
// the mask merge happens after the Ps read, in A-layout.
__global__ __launch_bounds__(256, 2) void k_attn(const ushort* __restrict__ Q2,
                                                 const ushort* __restrict__ K3,
                                                 const ushort* __restrict__ Vt,
                                                 const uint* __restrict__ pm,
                                                 const float* __restrict__ Wsp,
                                                 const float* __restrict__ lse,
                                                 float* __restrict__ out) {
    const int bid = blockIdx.x;
    const int id = (bid & 7) * 64 + (bid >> 3);   // XCD-contiguous remap (512 = 8*64)
    const int h = id >> 5;
    const int s0 = (id & 31) * 64;
    const int tid = threadIdx.x;
    const int wv = tid >> 6, lane = tid & 63;
    const int ln = lane & 15, quad = lane >> 4;
    __shared__ ushort K3s[64][72];
    __shared__ ushort Vts[128][72];
    __shared__ ushort Ps[4][16][72];

    const ushort* K3h = K3 + (size_t)h * S * DKER;
    const ushort* Vth = Vt + (size_t)h * DH * S;
    const int srow_q = s0 + wv * 16 + quad * 4;   // C/D-layout base row
    const int arow   = s0 + wv * 16 + ln;         // A-layout row
    const int rk = tid >> 3, ck = tid & 7;        // staging coords

    const float* Wr = Wsp + (size_t)h * S * S + (size_t)arow * S;
    const uint*  pr = pm + (size_t)arow * 64;

    // loop-invariant Q2 A-fragments, direct from global
    bf16x8 aq[2];
    #pragma unroll
    for (int ks = 0; ks < 2; ++ks)
        aq[ks] = *(const bf16x8*)(Q2 + ((size_t)h * S + arow) * DKER +
                                  ks * 32 + quad * 8);

    f32x4 O[8];
    #pragma unroll
    for (int v = 0; v < 8; ++v) O[v] = (f32x4){0.f, 0.f, 0.f, 0.f};
    float rs[4] = {0.f, 0.f, 0.f, 0.f};

    bf16x8 sk[2][2], sv[2][4];   // [parity][chunk] staged K3 / Vt tiles
    uint2  mw[2][4];             // [parity][r] C/D-layout mask words
    float4 wbuf[2][4];           // [slot] Wsp A-layout (2-deep rotation)
    uint2  mwa[2];               // [slot] A-layout mask words

#define PREF_W(T, SL) do {                                                         \
    if ((T) < 32) {                                                                \
        const float* wp_ = Wr + (T) * 64 + quad * 8;                               \
        wbuf[SL][0] = *(const float4*)wp_;                                         \
        wbuf[SL][1] = *(const float4*)(wp_ + 4);                                   \
        wbuf[SL][2] = *(const float4*)(wp_ + 32);                                  \
        wbuf[SL][3] = *(const float4*)(wp_ + 36);                                  \
        mwa[SL] = *(const uint2*)(pr + (T) * 2);                                   \
    }                                                                              \
} while (0)

#define PREF_KV(T, P) do {                                                         \
    if ((T) < 32) {                                                                \
        const int t0_ = (T) * 64;                                                  \
        _Pragma("unroll") for (int c_ = 0; c_ < 2; ++c_)                           \
            sk[P][c_] = *(const bf16x8*)(K3h +                                     \
                (size_t)(t0_ + rk + c_ * 32) * DKER + ck * 8);                     \
        _Pragma("unroll") for (int c_ = 0; c_ < 4; ++c_)                           \
            sv[P][c_] = *(const bf16x8*)(Vth +                                     \
                (size_t)(rk + c_ * 32) * S + t0_ + ck * 8);                        \
        _Pragma("unroll") for (int r_ = 0; r_ < 4; ++r_)                           \
            mw[P][r_] = *(const uint2*)(pm + (size_t)(srow_q + r_) * 64 +          \
                                        (T) * 2);                                  \
    }                                                                              \
} while (0)

#define STEP(T, P, PN) do {                                                        \
    __syncthreads();  /* prior LDS consumers done */                               \
    _Pragma("unroll") for (int c_ = 0; c_ < 2; ++c_)                               \
        *(bf16x8*)&K3s[rk + c_ * 32][ck * 8] = sk[P][c_];                          \
    _Pragma("unroll") for (int c_ = 0; c_ < 4; ++c_)                               \
        *(bf16x8*)&Vts[rk + c_ * 32][ck * 8] = sv[P][c_];                          \
    __syncthreads();  /* staged tile visible */                                    \
    PREF_KV((T) + 1, PN);                                                          \
    f32x4 sc[4];                                                                   \
    _Pragma("unroll") for (int n_ = 0; n_ < 4; ++n_)                               \
        sc[n_] = (f32x4){0.f, 0.f, 0.f, 0.f};                                      \
    _Pragma("unroll") for (int ks_ = 0; ks_ < 2; ++ks_)                            \
    _Pragma("unroll") for (int n_ = 0; n_ < 4; ++n_) {                             \
        bf16x8 bf = *(const bf16x8*)&K3s[n_ * 16 + ln][ks_ * 32 + quad * 8];       \
        sc[n_] = __builtin_amdgcn_mfma_f32_16x16x32_bf16(aq[ks_], bf, sc[n_],      \
                                                         0, 0, 0);                  \
    }                                                                              \
    _Pragma("unroll") for (int n_ = 0; n_ < 4; ++n_)                               \
    _Pragma("unroll") for (int r_ = 0; r_ < 4; ++r_) {                             \
        uint word = (n_ >= 2) ? mw[P][r_].y : mw[P][r_].x;                         \
        int m_ = (word >> (((n_ & 1) << 4) + ln)) & 1;                             \
        float s_ = sc[n_][r_];                                                     \
        if (m_) rs[r_] += s_;                                                      \
        Ps[wv][quad * 4 + r_][n_ * 16 + ln] = f2b(s_);                             \
    }                                                                              \
    /* A-layout merge: Ps read (same-wave DS order) + Wsp slot (T)&1 */            \
    bf16x8 pa0, pa1;                                                               \
    {                                                                              \
        bf16x8 ps0 = *(const bf16x8*)&Ps[wv][ln][quad * 8];                        \
        bf16x8 ps1 = *(const bf16x8*)&Ps[wv][ln][32 + quad * 8];                   \
        uint2 ma_ = mwa[(T) & 1];                                                  \
        pa0 = merge8(ps0, ma_.x >> (quad * 8), wbuf[(T) & 1][0],                   \
                     wbuf[(T) & 1][1]);                                            \
        pa1 = merge8(ps1, ma_.y >> (quad * 8), wbuf[(T) & 1][2],                   \
                     wbuf[(T) & 1][3]);                                            \
    }                                                                              \
    PREF_W((T) + 2, (T) & 1);  /* refill slot for iteration T+2 */                 \
    _Pragma("unroll") for (int v_ = 0; v_ < 8; ++v_) {                             \
        bf16x8 vf = *(const bf16x8*)&Vts[v_ * 16 + ln][quad * 8];                  \
        O[v_] = __builtin_amdgcn_mfma_f32_16x16x32_bf16(pa0, vf, O[v_], 0, 0, 0);  \
    }                                                                              \
    _Pragma("unroll") for (int v_ = 0; v_ < 8; ++v_) {                             \
        bf16x8 vf = *(const bf16x8*)&Vts[v_ * 16 + ln][32 + quad * 8];             \
        O[v_] = __builtin_amdgcn_mfma_f32_16x16x32_bf16(pa1, vf, O[v_], 0, 0, 0);  \
    }                                                                              \
} while (0)

    PREF_W(0, 0);
    PREF_W(1, 1);
    PREF_KV(0, 0);
    for (int it = 0; it < 32; it += 2) {
        STEP(it, 0, 1);
        STEP(it + 1, 1, 0);
    }
#undef PREF_W
#undef PREF_KV
#undef STEP

    // rowsum across the 16 lanes sharing each C/D row
    #pragma unroll
    for (int r = 0; r < 4; ++r) {
        float v = rs[r];
        v += __shfl_xor(v, 1); v += __shfl_xor(v, 2);
        v += __shfl_xor(v, 4); v += __shfl_xor(v, 8);
        rs[r] = v;
    }
    float idv[4];
    #pragma unroll
    for (int r = 0; r < 4; ++r)
        idv[r] = 1.f / (rs[r] + EPSF + expf(lse[(size_t)h * S + srow_q + r]));
    #pragma unroll
    for (int v = 0; v < 8; ++v)
        #pragma unroll
        for (int r = 0; r < 4; ++r)
            out[(size_t)(srow_q + r) * DD + h * DH + v * 16 + ln] = O[v][r] * idv[r];
}

extern "C" void kernel_launch(void* const* d_in, const int* in_sizes, int n_in,
                              void* d_out, int out_size, void* d_ws, size_t ws_size,
                              hipStream_t stream) {
    const float* q   = (const float*)d_in[0];
    const float* k   = (const float*)d_in[1];
    const float* v   = (const float*)d_in[2];
    const int*   msk = (const int*)d_in[3];
    const float* lse = (const float*)d_in[4];
    const float* spw = (const float*)d_in[5];
    const float* wq1 = (const float*)d_in[6];
    const float* wk1 = (const float*)d_in[7];
    const float* wq2 = (const float*)d_in[8];
    const float* wk2 = (const float*)d_in[9];
    const float* ik  = (const float*)d_in[10];
    const float* sD  = (const float*)d_in[11];
    const float* sD2 = (const float*)d_in[12];
    float* out = (float*)d_out;

    ushort* q2b  = (ushort*)d_ws;                          // 16*2048*64
    ushort* k3b  = q2b + (size_t)NH * S * DKER;            // 16*2048*64
    ushort* vt   = k3b + (size_t)NH * S * DKER;            // 16*128*2048
    uint*   pm   = (uint*)(vt + (size_t)NH * DH * S);      // 2048*64
    ushort* w1qt = (ushort*)(pm + (size_t)S * 64);         // 16*128*128
    ushort* w1kt = w1qt + (size_t)NH * DH * DHID;
    ushort* w2qt = w1kt + (size_t)NH * DH * DHID;          // 16*64*128
    ushort* w2kt = w2qt + (size_t)NH * DKER * DHID;
    ushort* ikt  = w2kt + (size_t)NH * DKER * DHID;        // 16*64*64

    dim3 g(S / 64, NH), b(256);
    k_wprep<<<dim3(NH, 5), b, 0, stream>>>(wq1, wk1, wq2, wk2, ik,
                                           w1qt, w1kt, w2qt, w2kt, ikt);
    k_mpack<<<dim3(S * 32 / 4), b, 0, stream>>>(msk, pm);
    k_vt<<<g, b, 0, stream>>>(v, vt);
    k_fused<<<dim3(S / 64, NH, 2), b, 0, stream>>>(q, k, w1qt, w1kt, w2qt, w2kt,
                                                   ikt, sD, sD2, q2b, k3b);
    k_attn<<<dim3(512), b, 0, stream>>>(q2b, k3b, vt, pm, spw, lse, out);
}

// Round 5
// 499.911 us; speedup vs baseline: 1.4940x; 1.0036x over previous
//
#include <hip/hip_runtime.h>
#include <math.h>

#define S 2048
#define DD 2048
#define NH 16
#define DH 128
#define DHID 128
#define DKER 64
#define EPSF 1e-6f

typedef __attribute__((ext_vector_type(8))) short bf16x8;
typedef __attribute__((ext_vector_type(4))) float f32x4;

__device__ __forceinline__ float gelu_f(float x) {
    return 0.5f * x * (1.0f + erff(x * 0.7071067811865475f));
}

__device__ __forceinline__ ushort f2b(float x) {
    uint32_t u = __float_as_uint(x);
    uint32_t r = (u + 0x7FFFu + ((u >> 16) & 1u)) >> 16;
    return (ushort)r;
}

__device__ __forceinline__ bf16x8 pack8(float4 a, float4 b) {
    bf16x8 r;
    r[0] = (short)f2b(a.x); r[1] = (short)f2b(a.y);
    r[2] = (short)f2b(a.z); r[3] = (short)f2b(a.w);
    r[4] = (short)f2b(b.x); r[5] = (short)f2b(b.y);
    r[6] = (short)f2b(b.z); r[7] = (short)f2b(b.w);
    return r;
}

// merge LR score (bf16, A-layout) with sparse exp(w) under mask bits
__device__ __forceinline__ bf16x8 merge8(bf16x8 ps, uint mb, float4 wa, float4 wb) {
    float w[8] = {wa.x, wa.y, wa.z, wa.w, wb.x, wb.y, wb.z, wb.w};
    float p[8];
    #pragma unroll
    for (int j = 0; j < 8; ++j) {
        float sv = __uint_as_float(((uint)(ushort)ps[j]) << 16);
        p[j] = ((mb >> j) & 1) ? (sv + EPSF) : __expf(w[j]);
    }
    return pack8(make_float4(p[0], p[1], p[2], p[3]),
                 make_float4(p[4], p[5], p[6], p[7]));
}

// ---- weight prep: transpose+convert to bf16 [out_dim][in_dim] ----
__global__ __launch_bounds__(256) void k_wprep(const float* __restrict__ wq1,
                                               const float* __restrict__ wk1,
                                               const float* __restrict__ wq2,
                                               const float* __restrict__ wk2,
                                               const float* __restrict__ ik,
                                               ushort* __restrict__ w1qt,
                                               ushort* __restrict__ w1kt,
                                               ushort* __restrict__ w2qt,
                                               ushort* __restrict__ w2kt,
                                               ushort* __restrict__ ikt) {
    const int h = blockIdx.x, m = blockIdx.y, tid = threadIdx.x;
    const float* src; ushort* dst; int D;
    if (m == 0)      { src = wq1 + h * 16384; dst = w1qt + h * 16384; D = 128; }
    else if (m == 1) { src = wk1 + h * 16384; dst = w1kt + h * 16384; D = 128; }
    else if (m == 2) { src = wq2 + h * 8192;  dst = w2qt + h * 8192;  D = 128; }
    else if (m == 3) { src = wk2 + h * 8192;  dst = w2kt + h * 8192;  D = 128; }
    else             { src = ik  + h * 4096;  dst = ikt  + h * 4096;  D = 64;  }
    const int E = (m == 0 || m == 1) ? 128 : 64;
    const int dsh = (D == 128) ? 7 : 6;
    const int n = E * D;
    for (int idx = tid; idx < n; idx += 256) {
        int e = idx >> dsh, d = idx & (D - 1);
        dst[idx] = f2b(src[d * E + e]);
    }
}

// ---- fused MLP paths: z=0 -> Q2abs, z=1 -> K3abs ----
__global__ __launch_bounds__(256) void k_fused(const float* __restrict__ Xq,
                                               const float* __restrict__ Xk,
                                               const ushort* __restrict__ w1qt,
                                               const ushort* __restrict__ w1kt,
                                               const ushort* __restrict__ w2qt,
                                               const ushort* __restrict__ w2kt,
                                               const ushort* __restrict__ ikt,
                                               const float* __restrict__ sD,
                                               const float* __restrict__ sD2,
                                               ushort* __restrict__ Q2,
                                               ushort* __restrict__ K3) {
    const int h = blockIdx.y;
    const int s0 = blockIdx.x * 64;
    const int z = blockIdx.z;
    const int tid = threadIdx.x;
    const int wv = tid >> 6, lane = tid & 63;
    const int ln = lane & 15, quad = lane >> 4;
    __shared__ ushort Y1s[64][136];   // 272B row ≡ 4 dw mod 32 banks
    __shared__ ushort K2s[64][72];

    const float* X = z ? Xk : Xq;
    const ushort* w1t = z ? w1kt : w1qt;
    const ushort* w2t = z ? w2kt : w2qt;

    // A1: X rows (fp32 -> bf16), direct from global
    const float* Xr = X + (size_t)(s0 + wv * 16 + ln) * DD + h * DH;
    bf16x8 a1[4];
    #pragma unroll
    for (int ks = 0; ks < 4; ++ks)
        a1[ks] = pack8(*(const float4*)(Xr + ks * 32 + quad * 8),
                       *(const float4*)(Xr + ks * 32 + quad * 8 + 4));

    // mlp1: 64x128 @ 128x128
    const ushort* W1h = w1t + (size_t)h * DH * DHID;
    f32x4 c1[8];
    #pragma unroll
    for (int n = 0; n < 8; ++n) c1[n] = (f32x4){0.f, 0.f, 0.f, 0.f};
    #pragma unroll
    for (int ks = 0; ks < 4; ++ks) {
        bf16x8 bb[8];
        #pragma unroll
        for (int n = 0; n < 8; ++n)
            bb[n] = *(const bf16x8*)(W1h + (size_t)(n * 16 + ln) * DHID +
                                     ks * 32 + quad * 8);
        #pragma unroll
        for (int n = 0; n < 8; ++n)
            c1[n] = __builtin_amdgcn_mfma_f32_16x16x32_bf16(a1[ks], bb[n], c1[n], 0, 0, 0);
    }
    #pragma unroll
    for (int n = 0; n < 8; ++n)
        #pragma unroll
        for (int r = 0; r < 4; ++r)
            Y1s[wv * 16 + quad * 4 + r][n * 16 + ln] = f2b(gelu_f(c1[n][r]));

    // mlp2: 64x128 @ 128x64  (rows are wave-private; same-wave DS ordering)
    bf16x8 a2[4];
    #pragma unroll
    for (int ks = 0; ks < 4; ++ks)
        a2[ks] = *(const bf16x8*)&Y1s[wv * 16 + ln][ks * 32 + quad * 8];
    const ushort* W2h = w2t + (size_t)h * DKER * DHID;
    f32x4 c2[4];
    #pragma unroll
    for (int n = 0; n < 4; ++n) c2[n] = (f32x4){0.f, 0.f, 0.f, 0.f};
    #pragma unroll
    for (int ks = 0; ks < 4; ++ks) {
        bf16x8 bb[4];
        #pragma unroll
        for (int n = 0; n < 4; ++n)
            bb[n] = *(const bf16x8*)(W2h + (size_t)(n * 16 + ln) * DHID +
                                     ks * 32 + quad * 8);
        #pragma unroll
        for (int n = 0; n < 4; ++n)
            c2[n] = __builtin_amdgcn_mfma_f32_16x16x32_bf16(a2[ks], bb[n], c2[n], 0, 0, 0);
    }

    if (z == 0) {
        #pragma unroll
        for (int n = 0; n < 4; ++n)
            #pragma unroll
            for (int r = 0; r < 4; ++r)
                Q2[((size_t)h * S + s0 + wv * 16 + quad * 4 + r) * DKER + n * 16 + ln] =
                    f2b(fabsf(gelu_f(c2[n][r])));
        return;
    }

    // k path: k2 = |sD| * gelu; k3 = |k2 + (k2 @ Ik) * sD2|
    float k2v[4][4];
    float sdv[4], sd2v[4];
    #pragma unroll
    for (int n = 0; n < 4; ++n) {
        sdv[n]  = fabsf(sD[h * DKER + n * 16 + ln]);
        sd2v[n] = sD2[h * DKER + n * 16 + ln];
    }
    #pragma unroll
    for (int n = 0; n < 4; ++n)
        #pragma unroll
        for (int r = 0; r < 4; ++r) {
            k2v[n][r] = sdv[n] * gelu_f(c2[n][r]);
            K2s[wv * 16 + quad * 4 + r][n * 16 + ln] = f2b(k2v[n][r]);
        }
    bf16x8 a3[2];
    #pragma unroll
    for (int ks = 0; ks < 2; ++ks)
        a3[ks] = *(const bf16x8*)&K2s[wv * 16 + ln][ks * 32 + quad * 8];
    const ushort* Ikh = ikt + (size_t)h * DKER * DKER;
    f32x4 c3[4];
    #pragma unroll
    for (int n = 0; n < 4; ++n) c3[n] = (f32x4){0.f, 0.f, 0.f, 0.f};
    #pragma unroll
    for (int ks = 0; ks < 2; ++ks) {
        bf16x8 bb[4];
        #pragma unroll
        for (int n = 0; n < 4; ++n)
            bb[n] = *(const bf16x8*)(Ikh + (size_t)(n * 16 + ln) * DKER +
                                     ks * 32 + quad * 8);
        #pragma unroll
        for (int n = 0; n < 4; ++n)
            c3[n] = __builtin_amdgcn_mfma_f32_16x16x32_bf16(a3[ks], bb[n], c3[n], 0, 0, 0);
    }
    #pragma unroll
    for (int n = 0; n < 4; ++n)
        #pragma unroll
        for (int r = 0; r < 4; ++r)
            K3[((size_t)h * S + s0 + wv * 16 + quad * 4 + r) * DKER + n * 16 + ln] =
                f2b(fabsf(k2v[n][r] + c3[n][r] * sd2v[n]));
}

// ---- Vt[h][c][t] = bf16( V[t][h*128+c] ) ----
__global__ __launch_bounds__(256) void k_vt(const float* __restrict__ V,
                                            ushort* __restrict__ Vt) {
    const int h = blockIdx.y;
    const int t0 = blockIdx.x * 64;
    const int tid = threadIdx.x;
    __shared__ ushort Ls[128][72];
    #pragma unroll
    for (int it = 0; it < 8; ++it) {
        int idx = it * 256 + tid;
        int r = idx >> 5, c4 = idx & 31;
        float4 v = *(const float4*)(V + (size_t)(t0 + r) * DD + h * DH + c4 * 4);
        Ls[c4 * 4 + 0][r] = f2b(v.x);
        Ls[c4 * 4 + 1][r] = f2b(v.y);
        Ls[c4 * 4 + 2][r] = f2b(v.z);
        Ls[c4 * 4 + 3][r] = f2b(v.w);
    }
    __syncthreads();
    #pragma unroll
    for (int it = 0; it < 4; ++it) {
        int idx = it * 256 + tid;
        int row = idx >> 3, cc = idx & 7;
        *(bf16x8*)(Vt + ((size_t)h * DH + row) * S + t0 + cc * 8) =
            *(const bf16x8*)(&Ls[row][cc * 8]);
    }
}

// ---- pack mask bits ----
__global__ __launch_bounds__(256) void k_mpack(const int* __restrict__ mask,
                                               uint* __restrict__ pm) {
    const int gw = blockIdx.x * 4 + (threadIdx.x >> 6);
    const int lane = threadIdx.x & 63;
    const int row = gw >> 5;
    const int w64 = gw & 31;
    int mv = mask[(size_t)row * S + w64 * 64 + lane];
    unsigned long long b = __ballot(mv != 0);
    if (lane == 0)  pm[row * 64 + w64 * 2]     = (uint)b;
    if (lane == 32) pm[row * 64 + w64 * 2 + 1] = (uint)(b >> 32);
}

// ---- fused attention: merged P = mask ? s_lr+eps : exp(w), one PV pass ----
// Same structure as round 4, but RAW s_barrier (no vmcnt drain): barrier (A)
// is a plain s_barrier (prev readers done via register deps); barrier (B) is
// lgkmcnt(0)+s_barrier (DS writes visible). The compiler's counted vmcnt
// waits then keep the 2-deep Wsp HBM prefetch in flight ACROSS barriers —
// issue order KV(T+1) first, W(T+2) second, so the sk/sv wait is vmcnt(5),
// never 0. This removes the ~per-iteration cold-HBM drain stall.
__global__ __launch_bounds__(256, 2) void k_attn(const ushort* __restrict__ Q2,
                                                 const ushort* __restrict__ K3,
                                                 const ushort* __restrict__ Vt,
                                                 const uint* __restrict__ pm,
                                                 const float* __restrict__ Wsp,
                                                 const float* __restrict__ lse,
                                                 float* __restrict__ out) {
    const int bid = blockIdx.x;
    const int id = (bid & 7) * 64 + (bid >> 3);   // XCD-contiguous remap (512 = 8*64)
    const int h = id >> 5;
    const int s0 = (id & 31) * 64;
    const int tid = threadIdx.x;
    const int wv = tid >> 6, lane = tid & 63;
    const int ln = lane & 15, quad = lane >> 4;
    __shared__ ushort K3s[64][72];
    __shared__ ushort Vts[128][72];
    __shared__ ushort Ps[4][16][72];

    const ushort* K3h = K3 + (size_t)h * S * DKER;
    const ushort* Vth = Vt + (size_t)h * DH * S;
    const int srow_q = s0 + wv * 16 + quad * 4;   // C/D-layout base row
    const int arow   = s0 + wv * 16 + ln;         // A-layout row
    const int rk = tid >> 3, ck = tid & 7;        // staging coords

    const float* Wr = Wsp + (size_t)h * S * S + (size_t)arow * S;
    const uint*  pr = pm + (size_t)arow * 64;

    // loop-invariant Q2 A-fragments, direct from global
    bf16x8 aq[2];
    #pragma unroll
    for (int ks = 0; ks < 2; ++ks)
        aq[ks] = *(const bf16x8*)(Q2 + ((size_t)h * S + arow) * DKER +
                                  ks * 32 + quad * 8);

    f32x4 O[8];
    #pragma unroll
    for (int v = 0; v < 8; ++v) O[v] = (f32x4){0.f, 0.f, 0.f, 0.f};
    float rs[4] = {0.f, 0.f, 0.f, 0.f};

    bf16x8 sk[2][2], sv[2][4];   // [parity][chunk] staged K3 / Vt tiles
    uint2  mw[2][4];             // [parity][r] C/D-layout mask words
    float4 wbuf[2][4];           // [slot] Wsp A-layout (2-deep rotation)
    uint2  mwa[2];               // [slot] A-layout mask words

#define PREF_W(T, SL) do {                                                         \
    if ((T) < 32) {                                                                \
        const float* wp_ = Wr + (T) * 64 + quad * 8;                               \
        wbuf[SL][0] = *(const float4*)wp_;                                         \
        wbuf[SL][1] = *(const float4*)(wp_ + 4);                                   \
        wbuf[SL][2] = *(const float4*)(wp_ + 32);                                  \
        wbuf[SL][3] = *(const float4*)(wp_ + 36);                                  \
        mwa[SL] = *(const uint2*)(pr + (T) * 2);                                   \
    }                                                                              \
} while (0)

#define PREF_KV(T, P) do {                                                         \
    if ((T) < 32) {                                                                \
        const int t0_ = (T) * 64;                                                  \
        _Pragma("unroll") for (int c_ = 0; c_ < 2; ++c_)                           \
            sk[P][c_] = *(const bf16x8*)(K3h +                                     \
                (size_t)(t0_ + rk + c_ * 32) * DKER + ck * 8);                     \
        _Pragma("unroll") for (int c_ = 0; c_ < 4; ++c_)                           \
            sv[P][c_] = *(const bf16x8*)(Vth +                                     \
                (size_t)(rk + c_ * 32) * S + t0_ + ck * 8);                        \
        _Pragma("unroll") for (int r_ = 0; r_ < 4; ++r_)                           \
            mw[P][r_] = *(const uint2*)(pm + (size_t)(srow_q + r_) * 64 +          \
                                        (T) * 2);                                  \
    }                                                                              \
} while (0)

#define STEP(T, P, PN, SL) do {                                                    \
    /* (A) all waves finished reading the previous staged tile (their      */      \
    /* ds_reads were consumed by MFMAs via register deps before this point)*/      \
    asm volatile("" ::: "memory");                                                 \
    __builtin_amdgcn_s_barrier();                                                  \
    asm volatile("" ::: "memory");                                                 \
    _Pragma("unroll") for (int c_ = 0; c_ < 2; ++c_)                               \
        *(bf16x8*)&K3s[rk + c_ * 32][ck * 8] = sk[P][c_];                          \
    _Pragma("unroll") for (int c_ = 0; c_ < 4; ++c_)                               \
        *(bf16x8*)&Vts[rk + c_ * 32][ck * 8] = sv[P][c_];                          \
    /* (B) DS writes committed, then barrier — no vmcnt drain              */      \
    asm volatile("s_waitcnt lgkmcnt(0)" ::: "memory");                             \
    __builtin_amdgcn_s_barrier();                                                  \
    asm volatile("" ::: "memory");                                                 \
    PREF_KV((T) + 1, PN);                                                          \
    f32x4 sc[4];                                                                   \
    _Pragma("unroll") for (int n_ = 0; n_ < 4; ++n_)                               \
        sc[n_] = (f32x4){0.f, 0.f, 0.f, 0.f};                                      \
    _Pragma("unroll") for (int ks_ = 0; ks_ < 2; ++ks_)                            \
    _Pragma("unroll") for (int n_ = 0; n_ < 4; ++n_) {                             \
        bf16x8 bf = *(const bf16x8*)&K3s[n_ * 16 + ln][ks_ * 32 + quad * 8];       \
        sc[n_] = __builtin_amdgcn_mfma_f32_16x16x32_bf16(aq[ks_], bf, sc[n_],      \
                                                         0, 0, 0);                  \
    }                                                                              \
    _Pragma("unroll") for (int n_ = 0; n_ < 4; ++n_)                               \
    _Pragma("unroll") for (int r_ = 0; r_ < 4; ++r_) {                             \
        uint word = (n_ >= 2) ? mw[P][r_].y : mw[P][r_].x;                         \
        int m_ = (word >> (((n_ & 1) << 4) + ln)) & 1;                             \
        float s_ = sc[n_][r_];                                                     \
        if (m_) rs[r_] += s_;                                                      \
        Ps[wv][quad * 4 + r_][n_ * 16 + ln] = f2b(s_);                             \
    }                                                                              \
    /* A-layout merge: Ps read (same-wave DS order) + Wsp slot SL */               \
    bf16x8 pa0, pa1;                                                               \
    {                                                                              \
        bf16x8 ps0 = *(const bf16x8*)&Ps[wv][ln][quad * 8];                        \
        bf16x8 ps1 = *(const bf16x8*)&Ps[wv][ln][32 + quad * 8];                   \
        uint2 ma_ = mwa[SL];                                                       \
        pa0 = merge8(ps0, ma_.x >> (quad * 8), wbuf[SL][0], wbuf[SL][1]);          \
        pa1 = merge8(ps1, ma_.y >> (quad * 8), wbuf[SL][2], wbuf[SL][3]);          \
    }                                                                              \
    PREF_W((T) + 2, SL);  /* refill slot for iteration T+2 */                      \
    _Pragma("unroll") for (int v_ = 0; v_ < 8; ++v_) {                             \
        bf16x8 vf = *(const bf16x8*)&Vts[v_ * 16 + ln][quad * 8];                  \
        O[v_] = __builtin_amdgcn_mfma_f32_16x16x32_bf16(pa0, vf, O[v_], 0, 0, 0);  \
    }                                                                              \
    _Pragma("unroll") for (int v_ = 0; v_ < 8; ++v_) {                             \
        bf16x8 vf = *(const bf16x8*)&Vts[v_ * 16 + ln][32 + quad * 8];             \
        O[v_] = __builtin_amdgcn_mfma_f32_16x16x32_bf16(pa1, vf, O[v_], 0, 0, 0);  \
    }                                                                              \
} while (0)

    PREF_W(0, 0);
    PREF_W(1, 1);
    PREF_KV(0, 0);
    for (int it = 0; it < 32; it += 2) {
        STEP(it, 0, 1, 0);
        STEP(it + 1, 1, 0, 1);
    }
#undef PREF_W
#undef PREF_KV
#undef STEP

    // rowsum across the 16 lanes sharing each C/D row
    #pragma unroll
    for (int r = 0; r < 4; ++r) {
        float v = rs[r];
        v += __shfl_xor(v, 1); v += __shfl_xor(v, 2);
        v += __shfl_xor(v, 4); v += __shfl_xor(v, 8);
        rs[r] = v;
    }
    float idv[4];
    #pragma unroll
    for (int r = 0; r < 4; ++r)
        idv[r] = 1.f / (rs[r] + EPSF + expf(lse[(size_t)h * S + srow_q + r]));
    #pragma unroll
    for (int v = 0; v < 8; ++v)
        #pragma unroll
        for (int r = 0; r < 4; ++r)
            out[(size_t)(srow_q + r) * DD + h * DH + v * 16 + ln] = O[v][r] * idv[r];
}

extern "C" void kernel_launch(void* const* d_in, const int* in_sizes, int n_in,
                              void* d_out, int out_size, void* d_ws, size_t ws_size,
                              hipStream_t stream) {
    const float* q   = (const float*)d_in[0];
    const float* k   = (const float*)d_in[1];
    const float* v   = (const float*)d_in[2];
    const int*   msk = (const int*)d_in[3];
    const float* lse = (const float*)d_in[4];
    const float* spw = (const float*)d_in[5];
    const float* wq1 = (const float*)d_in[6];
    const float* wk1 = (const float*)d_in[7];
    const float* wq2 = (const float*)d_in[8];
    const float* wk2 = (const float*)d_in[9];
    const float* ik  = (const float*)d_in[10];
    const float* sD  = (const float*)d_in[11];
    const float* sD2 = (const float*)d_in[12];
    float* out = (float*)d_out;

    ushort* q2b  = (ushort*)d_ws;                          // 16*2048*64
    ushort* k3b  = q2b + (size_t)NH * S * DKER;            // 16*2048*64
    ushort* vt   = k3b + (size_t)NH * S * DKER;            // 16*128*2048
    uint*   pm   = (uint*)(vt + (size_t)NH * DH * S);      // 2048*64
    ushort* w1qt = (ushort*)(pm + (size_t)S * 64);         // 16*128*128
    ushort* w1kt = w1qt + (size_t)NH * DH * DHID;
    ushort* w2qt = w1kt + (size_t)NH * DH * DHID;          // 16*64*128
    ushort* w2kt = w2qt + (size_t)NH * DKER * DHID;
    ushort* ikt  = w2kt + (size_t)NH * DKER * DHID;        // 16*64*64

    dim3 g(S / 64, NH), b(256);
    k_wprep<<<dim3(NH, 5), b, 0, stream>>>(wq1, wk1, wq2, wk2, ik,
                                           w1qt, w1kt, w2qt, w2kt, ikt);
    k_mpack<<<dim3(S * 32 / 4), b, 0, stream>>>(msk, pm);
    k_vt<<<g, b, 0, stream>>>(v, vt);
    k_fused<<<dim3(S / 64, NH, 2), b, 0, stream>>>(q, k, w1qt, w1kt, w2qt, w2kt,
                                                   ikt, sD, sD2, q2b, k3b);
    k_attn<<<dim3(512), b, 0, stream>>>(q2b, k3b, vt, pm, spw, lse, out);
}